// Round 1
// baseline (359.527 us; speedup 1.0000x reference)
//
#include <hip/hip_runtime.h>
#include <hip/hip_bf16.h>
#include <stdint.h>

// MHA forward, B=2 S=2048 D=1024 H=16 depth=64.
// Stage 1: QKV projections  (bf16 MFMA GEMM, fp32 in, bf16 head-major out)
// Stage 2: flash attention  (bf16 MFMA, online softmax fp32)
// Stage 3: output projection (bf16 MFMA GEMM, fp32 out + bias)

typedef __attribute__((ext_vector_type(8))) short bf16x8;
typedef __attribute__((ext_vector_type(4))) float f32x4;

#define MFMA16(a, b, c) __builtin_amdgcn_mfma_f32_16x16x32_bf16((a), (b), (c), 0, 0, 0)

static constexpr int S_LEN = 2048;
static constexpr int DM    = 1024;
static constexpr int DEPTH = 64;

__device__ __forceinline__ unsigned short f2b(float f) {
  unsigned u = __float_as_uint(f);
  unsigned r = 0x7FFFu + ((u >> 16) & 1u);   // RNE
  return (unsigned short)((u + r) >> 16);
}

// ---------------------------------------------------------------------------
// GEMM body: C[4096x1024] = A[4096x1024] * W[1024x1024] + bias
// 128x128 tile, BK=32, 4 waves (2x2), each wave 64x64 (4x4 MFMA tiles).
// MODE 0: A = fp32 (converted inline), store bf16 head-major [B*H][S][64]
// MODE 1: A = bf16, store fp32 row-major [4096][1024]
// LDS rows padded to 40 bf16 (80 B = 5*16 B): 16B-aligned, 2-way banks only.
// ---------------------------------------------------------------------------
template<int MODE>
__device__ __forceinline__ void gemm_body(const void* __restrict__ Ap,
                                          const float* __restrict__ W,
                                          const float* __restrict__ bias,
                                          void* __restrict__ Op) {
  __shared__ unsigned short Asl[128][40];
  __shared__ unsigned short Bsl[128][40];  // transposed: Bsl[n][k]

  const int bm = blockIdx.x, bn = blockIdx.y;
  const int tid = threadIdx.x;
  const int wave = tid >> 6, lane = tid & 63;
  const int wr = wave >> 1, wc = wave & 1;
  const int g = lane >> 4, i16 = lane & 15;

  f32x4 acc[4][4] = {};

  for (int k0 = 0; k0 < DM; k0 += 32) {
    // ---- stage A tile (128 x 32) ----
    if constexpr (MODE == 0) {
      const float* A = (const float*)Ap;
      #pragma unroll
      for (int i = 0; i < 4; ++i) {
        int idx = tid + i * 256;              // 1024 float4 slots
        int row = idx >> 3, c4 = (idx & 7) * 4;
        float4 vv = *(const float4*)&A[(size_t)(bm * 128 + row) * DM + k0 + c4];
        unsigned short* dst = &Asl[row][c4];
        dst[0] = f2b(vv.x); dst[1] = f2b(vv.y);
        dst[2] = f2b(vv.z); dst[3] = f2b(vv.w);
      }
    } else {
      const unsigned short* A = (const unsigned short*)Ap;
      #pragma unroll
      for (int i = 0; i < 2; ++i) {
        int idx = tid + i * 256;              // 512 slots of 8 bf16
        int row = idx >> 2, c8 = (idx & 3) * 8;
        bf16x8 vv = *(const bf16x8*)&A[(size_t)(bm * 128 + row) * DM + k0 + c8];
        *(bf16x8*)&Asl[row][c8] = vv;
      }
    }
    // ---- stage B tile (32 x 128), transposed into Bsl[n][k] ----
    #pragma unroll
    for (int i = 0; i < 4; ++i) {
      int idx = tid + i * 256;                // 1024 float4 slots
      int kr = idx >> 5, c4 = (idx & 31) * 4;
      float4 vv = *(const float4*)&W[(size_t)(k0 + kr) * DM + bn * 128 + c4];
      Bsl[c4 + 0][kr] = f2b(vv.x);
      Bsl[c4 + 1][kr] = f2b(vv.y);
      Bsl[c4 + 2][kr] = f2b(vv.z);
      Bsl[c4 + 3][kr] = f2b(vv.w);
    }
    __syncthreads();

    bf16x8 a[4], b[4];
    #pragma unroll
    for (int m = 0; m < 4; ++m)
      a[m] = *(const bf16x8*)&Asl[wr * 64 + m * 16 + i16][g * 8];
    #pragma unroll
    for (int n = 0; n < 4; ++n)
      b[n] = *(const bf16x8*)&Bsl[wc * 64 + n * 16 + i16][g * 8];
    #pragma unroll
    for (int m = 0; m < 4; ++m)
      #pragma unroll
      for (int n = 0; n < 4; ++n)
        acc[m][n] = MFMA16(a[m], b[n], acc[m][n]);
    __syncthreads();
  }

  // ---- epilogue: D layout col=lane&15, row=(lane>>4)*4+reg ----
  #pragma unroll
  for (int m = 0; m < 4; ++m) {
    #pragma unroll
    for (int n = 0; n < 4; ++n) {
      #pragma unroll
      for (int r = 0; r < 4; ++r) {
        int row = bm * 128 + wr * 64 + m * 16 + g * 4 + r;   // 0..4095 = b*2048+s
        int col = bn * 128 + wc * 64 + n * 16 + i16;         // 0..1023
        float v = acc[m][n][r] + bias[col];
        if constexpr (MODE == 0) {
          unsigned short* O = (unsigned short*)Op;           // [B*H][S][64]
          int b_ = row >> 11, s = row & 2047;
          int h = col >> 6, dd = col & 63;
          O[(((size_t)(b_ * 16 + h)) * S_LEN + s) * DEPTH + dd] = f2b(v);
        } else {
          float* O = (float*)Op;
          O[(size_t)row * DM + col] = v;
        }
      }
    }
  }
}

__global__ __launch_bounds__(256) void proj_qkv_k(
    const float* __restrict__ xq, const float* __restrict__ xk, const float* __restrict__ xv,
    const float* __restrict__ Wq, const float* __restrict__ Wk, const float* __restrict__ Wv,
    const float* __restrict__ bq, const float* __restrict__ bk, const float* __restrict__ bv,
    unsigned short* __restrict__ Qh, unsigned short* __restrict__ Kh, unsigned short* __restrict__ Vh) {
  const int z = blockIdx.z;
  const float* X = (z == 0) ? xq : (z == 1) ? xk : xv;
  const float* W = (z == 0) ? Wq : (z == 1) ? Wk : Wv;
  const float* B = (z == 0) ? bq : (z == 1) ? bk : bv;
  unsigned short* O = (z == 0) ? Qh : (z == 1) ? Kh : Vh;
  gemm_body<0>((const void*)X, W, B, (void*)O);
}

__global__ __launch_bounds__(256) void out_proj_k(
    const unsigned short* __restrict__ At, const float* __restrict__ Wo,
    const float* __restrict__ bo, float* __restrict__ out) {
  gemm_body<1>((const void*)At, Wo, bo, (void*)out);
}

// ---------------------------------------------------------------------------
// Flash attention: grid (32 q-tiles, 32 b*h), 4 waves/block, 16 q-rows/wave,
// KVBLK=32. QK^T: K row-major IS the B-fragment layout (16B loads).
// P goes D-layout -> A-layout through a per-wave padded LDS tile.
// ---------------------------------------------------------------------------
__global__ __launch_bounds__(256) void attn_k(
    const unsigned short* __restrict__ Qh, const unsigned short* __restrict__ Kh,
    const unsigned short* __restrict__ Vh, unsigned short* __restrict__ Ob) {
  __shared__ unsigned short p_lds[4][16][40];

  const int qt = blockIdx.x, bh = blockIdx.y;
  const int tid = threadIdx.x;
  const int wave = tid >> 6, lane = tid & 63;
  const int g = lane >> 4, i16 = lane & 15;

  const unsigned short* Q = Qh + (size_t)bh * S_LEN * DEPTH;
  const unsigned short* K = Kh + (size_t)bh * S_LEN * DEPTH;
  const unsigned short* V = Vh + (size_t)bh * S_LEN * DEPTH;

  const int qbase = qt * 64 + wave * 16;
  const bf16x8 qa0 = *(const bf16x8*)&Q[(size_t)(qbase + i16) * DEPTH + g * 8];
  const bf16x8 qa1 = *(const bf16x8*)&Q[(size_t)(qbase + i16) * DEPTH + 32 + g * 8];

  float m_run[4] = {-1e30f, -1e30f, -1e30f, -1e30f};
  float l_run[4] = {0.f, 0.f, 0.f, 0.f};
  f32x4 o[4] = {};

  for (int kv0 = 0; kv0 < S_LEN; kv0 += 32) {
    const bf16x8 k00 = *(const bf16x8*)&K[(size_t)(kv0 + i16) * DEPTH + g * 8];
    const bf16x8 k01 = *(const bf16x8*)&K[(size_t)(kv0 + i16) * DEPTH + 32 + g * 8];
    const bf16x8 k10 = *(const bf16x8*)&K[(size_t)(kv0 + 16 + i16) * DEPTH + g * 8];
    const bf16x8 k11 = *(const bf16x8*)&K[(size_t)(kv0 + 16 + i16) * DEPTH + 32 + g * 8];

    f32x4 s0 = {0.f, 0.f, 0.f, 0.f}, s1 = {0.f, 0.f, 0.f, 0.f};
    s0 = MFMA16(qa0, k00, s0); s0 = MFMA16(qa1, k01, s0);
    s1 = MFMA16(qa0, k10, s1); s1 = MFMA16(qa1, k11, s1);

    float mx[4], alpha[4], rs[4];
    #pragma unroll
    for (int r = 0; r < 4; ++r) {
      s0[r] *= 0.125f; s1[r] *= 0.125f;          // 1/sqrt(64)
      mx[r] = fmaxf(s0[r], s1[r]);
    }
    #pragma unroll
    for (int msk = 1; msk < 16; msk <<= 1)
      #pragma unroll
      for (int r = 0; r < 4; ++r)
        mx[r] = fmaxf(mx[r], __shfl_xor(mx[r], msk, 64));
    #pragma unroll
    for (int r = 0; r < 4; ++r) {
      float mn = fmaxf(m_run[r], mx[r]);
      alpha[r] = __expf(m_run[r] - mn);
      m_run[r] = mn;
      s0[r] = __expf(s0[r] - mn);
      s1[r] = __expf(s1[r] - mn);
      rs[r] = s0[r] + s1[r];
    }
    #pragma unroll
    for (int msk = 1; msk < 16; msk <<= 1)
      #pragma unroll
      for (int r = 0; r < 4; ++r)
        rs[r] += __shfl_xor(rs[r], msk, 64);
    #pragma unroll
    for (int r = 0; r < 4; ++r)
      l_run[r] = l_run[r] * alpha[r] + rs[r];
    #pragma unroll
    for (int dt = 0; dt < 4; ++dt)
      #pragma unroll
      for (int r = 0; r < 4; ++r)
        o[dt][r] *= alpha[r];

    // P: D-layout -> LDS (row = q-row, col = kv)
    #pragma unroll
    for (int r = 0; r < 4; ++r) {
      p_lds[wave][g * 4 + r][i16]      = f2b(s0[r]);
      p_lds[wave][g * 4 + r][16 + i16] = f2b(s1[r]);
    }
    __syncthreads();
    const bf16x8 pa = *(const bf16x8*)&p_lds[wave][i16][g * 8];

    #pragma unroll
    for (int dt = 0; dt < 4; ++dt) {
      bf16x8 vb;
      #pragma unroll
      for (int j = 0; j < 8; ++j)
        vb[j] = (short)V[(size_t)(kv0 + g * 8 + j) * DEPTH + dt * 16 + i16];
      o[dt] = MFMA16(pa, vb, o[dt]);
    }
    __syncthreads();
  }

  const int b_ = bh >> 4, h = bh & 15;
  #pragma unroll
  for (int dt = 0; dt < 4; ++dt) {
    #pragma unroll
    for (int r = 0; r < 4; ++r) {
      int qrow = qbase + g * 4 + r;
      float val = o[dt][r] / l_run[r];
      Ob[((size_t)(b_ * S_LEN + qrow)) * DM + h * DEPTH + dt * 16 + i16] = f2b(val);
    }
  }
}

extern "C" void kernel_launch(void* const* d_in, const int* in_sizes, int n_in,
                              void* d_out, int out_size, void* d_ws, size_t ws_size,
                              hipStream_t stream) {
  const float* q  = (const float*)d_in[0];
  const float* k  = (const float*)d_in[1];
  const float* v  = (const float*)d_in[2];
  const float* Wq = (const float*)d_in[3];
  const float* bq = (const float*)d_in[4];
  const float* Wk = (const float*)d_in[5];
  const float* bk = (const float*)d_in[6];
  const float* Wv = (const float*)d_in[7];
  const float* bv = (const float*)d_in[8];
  const float* Wo = (const float*)d_in[9];
  const float* bo = (const float*)d_in[10];
  float* out = (float*)d_out;

  // workspace: Qh, Kh, Vh head-major bf16 [32][2048][64], At bf16 [4096][1024]
  const size_t HEAD_ELEMS = (size_t)2 * 16 * S_LEN * DEPTH;  // 4,194,304
  unsigned short* Qh = (unsigned short*)d_ws;
  unsigned short* Kh = Qh + HEAD_ELEMS;
  unsigned short* Vh = Kh + HEAD_ELEMS;
  unsigned short* At = Vh + HEAD_ELEMS;

  dim3 blk(256);
  hipLaunchKernelGGL(proj_qkv_k, dim3(32, 8, 3), blk, 0, stream,
                     q, k, v, Wq, Wk, Wv, bq, bk, bv, Qh, Kh, Vh);
  hipLaunchKernelGGL(attn_k, dim3(32, 32), blk, 0, stream, Qh, Kh, Vh, At);
  hipLaunchKernelGGL(out_proj_k, dim3(32, 8), blk, 0, stream, At, Wo, bo, out);
}